// Round 7
// baseline (739.811 us; speedup 1.0000x reference)
//
#include <hip/hip_runtime.h>
#include <cstdint>

#define B_ 2
#define S_ 2048
#define D_ 1024
#define H_ 16
#define DH_ 64
#define FF_ 4096
#define M_TOK (B_ * S_)  // 4096 token rows

typedef __attribute__((ext_vector_type(8))) short short8;
typedef __attribute__((ext_vector_type(4))) float f32x4;
typedef __attribute__((ext_vector_type(4))) unsigned short us4;

typedef unsigned short u16;

__device__ __forceinline__ float bf2f(u16 u) {
  union { uint32_t u; float f; } x;
  x.u = ((uint32_t)u) << 16;
  return x.f;
}
__device__ __forceinline__ u16 f2bf(float f) {
  union { float f; uint32_t u; } x;
  x.f = f;
  uint32_t r = x.u + 0x7FFFu + ((x.u >> 16) & 1u);  // RNE
  return (u16)(r >> 16);
}
// convert 8 contiguous f32 -> short8 (bf16 bits)
__device__ __forceinline__ short8 cvt8(const float* p) {
  const float4 a = *(const float4*)p;
  const float4 b = *(const float4*)(p + 4);
  short8 r;
  r[0] = (short)f2bf(a.x); r[1] = (short)f2bf(a.y);
  r[2] = (short)f2bf(a.z); r[3] = (short)f2bf(a.w);
  r[4] = (short)f2bf(b.x); r[5] = (short)f2bf(b.y);
  r[6] = (short)f2bf(b.z); r[7] = (short)f2bf(b.w);
  return r;
}

// ---------------- RMSNorm: one block per token row (f32 in, bf16 out) ----------------
__global__ __launch_bounds__(256) void rmsnorm_k(const float* __restrict__ X,
                                                 const float* __restrict__ G,
                                                 u16* __restrict__ Hout) {
  const int row = blockIdx.x;
  const int tid = threadIdx.x;
  const float4 xx = *(const float4*)&X[(size_t)row * D_ + tid * 4];
  float v[4] = {xx.x, xx.y, xx.z, xx.w};
  float s = 0.f;
#pragma unroll
  for (int i = 0; i < 4; ++i) s += v[i] * v[i];
#pragma unroll
  for (int d = 1; d < 64; d <<= 1) s += __shfl_xor(s, d);
  __shared__ float red[4];
  if ((tid & 63) == 0) red[tid >> 6] = s;
  __syncthreads();
  s = red[0] + red[1] + red[2] + red[3];
  const float scale = rsqrtf(s * (1.0f / (float)D_) + 1e-5f);
  const float4 gg = *(const float4*)&G[tid * 4];
  us4 o;
  o[0] = f2bf(v[0] * scale * gg.x);
  o[1] = f2bf(v[1] * scale * gg.y);
  o[2] = f2bf(v[2] * scale * gg.z);
  o[3] = f2bf(v[3] * scale * gg.w);
  *(us4*)&Hout[(size_t)row * D_ + tid * 4] = o;
}

// ---------------- GEMM: C[M,N] = A[M,K](bf16) * W[N,K]^T(f32, cvt on the fly) ----------------
// 128x128 tile, BK=32. MODE 0: store; MODE 1: += RES(f32); MODE 2: gelu.
// TO = u16 (bf16 store) or float (f32 store).
#define LSTR 40
template <int MODE, typename TO>
__global__ __launch_bounds__(256) void gemm_bt_k(const u16* __restrict__ A,
                                                 const float* __restrict__ W,
                                                 const float* __restrict__ RES,
                                                 TO* __restrict__ C, int N, int K) {
  __shared__ alignas(16) u16 As[128 * LSTR];
  __shared__ alignas(16) u16 Bs[128 * LSTR];
  const int tid = threadIdx.x;
  const int wv = tid >> 6, lane = tid & 63;
  const int r = lane & 15, quad = lane >> 4;
  const int bm = blockIdx.y * 128, bn = blockIdx.x * 128;
  const int row0 = (wv >> 1) * 64, col0 = (wv & 1) * 64;

  f32x4 acc[4][4] = {};

  const int c0row = tid >> 2, cgrp = tid & 3;  // rows 0..63
  const int c1row = 64 + c0row;                // rows 64..127

  for (int k0 = 0; k0 < K; k0 += 32) {
    short8 a0 = *(const short8*)&A[(size_t)(bm + c0row) * K + k0 + cgrp * 8];
    short8 a1 = *(const short8*)&A[(size_t)(bm + c1row) * K + k0 + cgrp * 8];
    short8 b0 = cvt8(&W[(size_t)(bn + c0row) * K + k0 + cgrp * 8]);
    short8 b1 = cvt8(&W[(size_t)(bn + c1row) * K + k0 + cgrp * 8]);
    *(short8*)&As[c0row * LSTR + cgrp * 8] = a0;
    *(short8*)&As[c1row * LSTR + cgrp * 8] = a1;
    *(short8*)&Bs[c0row * LSTR + cgrp * 8] = b0;
    *(short8*)&Bs[c1row * LSTR + cgrp * 8] = b1;
    __syncthreads();
    short8 af[4], bf[4];
#pragma unroll
    for (int mt = 0; mt < 4; ++mt)
      af[mt] = *(const short8*)&As[(row0 + mt * 16 + r) * LSTR + quad * 8];
#pragma unroll
    for (int nt = 0; nt < 4; ++nt)
      bf[nt] = *(const short8*)&Bs[(col0 + nt * 16 + r) * LSTR + quad * 8];
#pragma unroll
    for (int mt = 0; mt < 4; ++mt)
#pragma unroll
      for (int nt = 0; nt < 4; ++nt)
        acc[mt][nt] = __builtin_amdgcn_mfma_f32_16x16x32_bf16(af[mt], bf[nt], acc[mt][nt], 0, 0, 0);
    __syncthreads();
  }

#pragma unroll
  for (int mt = 0; mt < 4; ++mt) {
#pragma unroll
    for (int nt = 0; nt < 4; ++nt) {
#pragma unroll
      for (int i = 0; i < 4; ++i) {
        const int grow = bm + row0 + mt * 16 + quad * 4 + i;
        const int gcol = bn + col0 + nt * 16 + r;
        float v = acc[mt][nt][i];
        if (MODE == 1) v += RES[(size_t)grow * N + gcol];
        if (MODE == 2) v = 0.5f * v * (1.0f + erff(v * 0.70710678118f));
        if constexpr (sizeof(TO) == 2) C[(size_t)grow * N + gcol] = f2bf(v);
        else                           C[(size_t)grow * N + gcol] = v;
      }
    }
  }
}

// ---------------- Flash attention: block = 64 q-rows of one (b,h); 4 waves x 16 rows ----------------
__global__ __launch_bounds__(256) void attn_k(const u16* __restrict__ Q,
                                              const u16* __restrict__ Kx,
                                              const u16* __restrict__ Vx,
                                              u16* __restrict__ O) {
  __shared__ alignas(16) u16 Ks[32 * 72];      // padded stride 72 u16
  __shared__ alignas(16) u16 Vs[64 * 40];      // V^T: [dh][key], padded stride 40 u16
  __shared__ alignas(16) u16 Ps[4 * 16 * 32];  // per-wave P tile (bf16, A-layout source)

  const int tid = threadIdx.x;
  const int wv = tid >> 6, lane = tid & 63;
  const int r = lane & 15, quad = lane >> 4;
  const int bh = blockIdx.y;
  const int b = bh >> 4, hh = bh & 15;
  const int qbase = blockIdx.x * 64;
  const size_t base = (size_t)b * S_ * D_ + (size_t)hh * DH_;
  const u16* Qb = Q + base;
  const u16* Kb = Kx + base;
  const u16* Vb = Vx + base;

  const int qrowA = qbase + wv * 16 + r;
  const short8 qf0 = *(const short8*)&Qb[(size_t)qrowA * D_ + quad * 8];
  const short8 qf1 = *(const short8*)&Qb[(size_t)qrowA * D_ + 32 + quad * 8];

  f32x4 oacc[4] = {};
  float m_i[4], l_i[4];
#pragma unroll
  for (int i = 0; i < 4; ++i) { m_i[i] = -INFINITY; l_i[i] = 0.f; }

  const int strow = tid >> 3, stkg = tid & 7;
  const int jend = qbase + 32;

  for (int j0 = 0; j0 <= jend; j0 += 32) {
    short8 kvv = *(const short8*)&Kb[(size_t)(j0 + strow) * D_ + stkg * 8];
    *(short8*)&Ks[strow * 72 + stkg * 8] = kvv;
    short8 vvv = *(const short8*)&Vb[(size_t)(j0 + strow) * D_ + stkg * 8];
#pragma unroll
    for (int jj = 0; jj < 8; ++jj) Vs[(stkg * 8 + jj) * 40 + strow] = (u16)vvv[jj];
    __syncthreads();

    float sv[2][4];
#pragma unroll
    for (int kt = 0; kt < 2; ++kt) {
      short8 kf0 = *(const short8*)&Ks[(kt * 16 + r) * 72 + quad * 8];
      short8 kf1 = *(const short8*)&Ks[(kt * 16 + r) * 72 + 32 + quad * 8];
      f32x4 z = {};
      z = __builtin_amdgcn_mfma_f32_16x16x32_bf16(qf0, kf0, z, 0, 0, 0);
      z = __builtin_amdgcn_mfma_f32_16x16x32_bf16(qf1, kf1, z, 0, 0, 0);
#pragma unroll
      for (int i = 0; i < 4; ++i) sv[kt][i] = z[i];
    }

#pragma unroll
    for (int i = 0; i < 4; ++i) {
      const int qidx = qbase + wv * 16 + quad * 4 + i;
      float v0 = (j0 + r > qidx) ? -INFINITY : sv[0][i] * 0.125f;
      float v1 = (j0 + 16 + r > qidx) ? -INFINITY : sv[1][i] * 0.125f;
      float mt_ = fmaxf(v0, v1);
#pragma unroll
      for (int d = 1; d < 16; d <<= 1) mt_ = fmaxf(mt_, __shfl_xor(mt_, d));
      const float mnew = fmaxf(m_i[i], mt_);
      float alpha, p0, p1;
      if (mnew == -INFINITY) {  // fully-masked so far
        alpha = 1.f; p0 = 0.f; p1 = 0.f;
      } else {
        alpha = (m_i[i] == -INFINITY) ? 0.f : __expf(m_i[i] - mnew);
        p0 = (v0 == -INFINITY) ? 0.f : __expf(v0 - mnew);
        p1 = (v1 == -INFINITY) ? 0.f : __expf(v1 - mnew);
      }
      float ps = p0 + p1;
#pragma unroll
      for (int d = 1; d < 16; d <<= 1) ps += __shfl_xor(ps, d);
      l_i[i] = l_i[i] * alpha + ps;
      m_i[i] = mnew;
#pragma unroll
      for (int nt = 0; nt < 4; ++nt) oacc[nt][i] *= alpha;
      Ps[wv * 512 + (quad * 4 + i) * 32 + r] = f2bf(p0);
      Ps[wv * 512 + (quad * 4 + i) * 32 + 16 + r] = f2bf(p1);
    }
    __syncthreads();

    const short8 pf = *(const short8*)&Ps[wv * 512 + r * 32 + quad * 8];
#pragma unroll
    for (int nt = 0; nt < 4; ++nt) {
      short8 vf = *(const short8*)&Vs[(nt * 16 + r) * 40 + quad * 8];
      oacc[nt] = __builtin_amdgcn_mfma_f32_16x16x32_bf16(pf, vf, oacc[nt], 0, 0, 0);
    }
    __syncthreads();
  }

#pragma unroll
  for (int nt = 0; nt < 4; ++nt)
#pragma unroll
    for (int i = 0; i < 4; ++i) {
      const int qidx = qbase + wv * 16 + quad * 4 + i;
      const float inv_l = (l_i[i] > 0.f) ? (1.0f / l_i[i]) : 0.f;
      O[base + (size_t)qidx * D_ + nt * 16 + r] = f2bf(oacc[nt][i] * inv_l);
    }
}

extern "C" void kernel_launch(void* const* d_in, const int* in_sizes, int n_in,
                              void* d_out, int out_size, void* d_ws, size_t ws_size,
                              hipStream_t stream) {
  (void)in_sizes; (void)n_in; (void)out_size; (void)ws_size;
  // Inputs f32; OUTPUT f32 (reference output dtype — the round-6 discovery).
  const float* x   = (const float*)d_in[0];
  const float* wq  = (const float*)d_in[1];
  const float* wk  = (const float*)d_in[2];
  const float* wvp = (const float*)d_in[3];
  const float* wo  = (const float*)d_in[4];
  const float* w1  = (const float*)d_in[5];
  const float* w2  = (const float*)d_in[6];
  const float* g1  = (const float*)d_in[7];
  const float* g2  = (const float*)d_in[8];
  float* out = (float*)d_out;  // also hosts x2 (f32 residual stream 2)

  // Workspace: 5 bf16 TD slots = 40 MB.
  u16* ws = (u16*)d_ws;
  const size_t TD = (size_t)M_TOK * D_;  // 4M elems
  u16* h  = ws;            // slot0: h, later o, later t[0]
  u16* q  = ws + 1 * TD;   // slot1: q, later t[1]
  u16* k  = ws + 2 * TD;   // slot2: k, later t[2]
  u16* v  = ws + 3 * TD;   // slot3: v, later t[3]
  u16* h2 = ws + 4 * TD;   // slot4: h2
  u16* o  = h;
  u16* t  = ws;            // spans slots 0..3 (h/o,q,k,v all dead by FFN1 store)

  const dim3 blk(256);
  const dim3 gD(D_ / 128, M_TOK / 128);   // (8, 32)
  const dim3 gF(FF_ / 128, M_TOK / 128);  // (32, 32)

  rmsnorm_k<<<M_TOK, blk, 0, stream>>>(x, g1, h);
  gemm_bt_k<0, u16><<<gD, blk, 0, stream>>>(h, wq, nullptr, q, D_, D_);
  gemm_bt_k<0, u16><<<gD, blk, 0, stream>>>(h, wk, nullptr, k, D_, D_);
  gemm_bt_k<0, u16><<<gD, blk, 0, stream>>>(h, wvp, nullptr, v, D_, D_);
  attn_k<<<dim3(S_ / 64, B_ * H_), blk, 0, stream>>>(q, k, v, o);
  gemm_bt_k<1, float><<<gD, blk, 0, stream>>>(o, wo, x, out, D_, D_);     // x2 = o@wo^T + x  (f32 -> d_out)
  rmsnorm_k<<<M_TOK, blk, 0, stream>>>(out, g2, h2);
  gemm_bt_k<2, u16><<<gF, blk, 0, stream>>>(h2, w1, nullptr, t, FF_, D_);
  gemm_bt_k<1, float><<<gD, blk, 0, stream>>>(t, w2, out, out, D_, FF_);  // out = t@w2^T + x2
}